// Round 13
// baseline (167.363 us; speedup 1.0000x reference)
//
#include <hip/hip_runtime.h>

typedef __attribute__((ext_vector_type(8))) short bf16x8;
typedef __attribute__((ext_vector_type(4))) float f32x4;
typedef unsigned short ushort_t;

#define N 4096

__device__ __forceinline__ unsigned short f2bf_rne(float f) {
  unsigned int u = __float_as_uint(f);
  u += 0x7fffu + ((u >> 16) & 1u);
  return (unsigned short)(u >> 16);
}

// One block per row (8192 rows: Z then Y). fp32 row norm + bf16 copy.
__global__ __launch_bounds__(256) void prep_kernel(
    const float* __restrict__ Z, const float* __restrict__ Y,
    ushort_t* __restrict__ Zb, ushort_t* __restrict__ Yb,
    float* __restrict__ norms) {
  const int r = blockIdx.x;
  const bool isZ = (r < N);
  const int rr = isZ ? r : r - N;
  const float* __restrict__ src = (isZ ? Z : Y) + (size_t)rr * N;
  ushort_t* __restrict__ dst = (isZ ? Zb : Yb) + (size_t)rr * N;
  const int t = threadIdx.x;

  float s = 0.f;
#pragma unroll
  for (int j = 0; j < 4; ++j) {
    const float4 v = ((const float4*)src)[j * 256 + t];
    s += v.x * v.x + v.y * v.y + v.z * v.z + v.w * v.w;
    short4 o;
    o.x = (short)f2bf_rne(v.x);
    o.y = (short)f2bf_rne(v.y);
    o.z = (short)f2bf_rne(v.z);
    o.w = (short)f2bf_rne(v.w);
    ((short4*)dst)[j * 256 + t] = o;
  }
#pragma unroll
  for (int off = 32; off > 0; off >>= 1) s += __shfl_down(s, off, 64);
  __shared__ float red[4];
  const int lane = t & 63, w = t >> 6;
  if (lane == 0) red[w] = s;
  __syncthreads();
  if (t == 0) norms[r] = sqrtf(red[0] + red[1] + red[2] + red[3]);
}

// ---- 128x256 tile, BK=32, 4 waves (1M x 4N), ring-3 LDS, 2 blocks/CU ----
// Wave = 128x64 (same shape as r11). LDS buf = 24KB: A[128][32]@0,
// B[256][32]@8192; bufs at 0/24576/49152 (72KB -> 2 blocks co-resident).
// Row = 64B = 4 slots; swizzle slot ^= ((row>>1)&3) (r2-proven, 0 conflicts).
// Per tile: {R2 | STG(T+2)} lgkm2 MF01 vmcnt6 BAR {R1(T+1)} lgkm10 MF23 BAR.
// Counted waits (r11); cross-block desync fills barrier/wait windows (m114).
__global__ __launch_bounds__(256, 2) void gemm_kernel(
    const ushort_t* __restrict__ A,   // Zb [N][N]
    const ushort_t* __restrict__ B,   // Yb [N][N]
    const float* __restrict__ norms,  // [2N]: nx then ny
    float* __restrict__ out) {
  __shared__ __align__(16) char smem[73728];

  const int bid = blockIdx.x;                 // 512 blocks; 512%8==0 bijective
  const int swz = (bid & 7) * 64 + (bid >> 3);
  const int tile_row = swz >> 4;              // 0..31 (M/128)
  const int tile_col = swz & 15;              // 0..15 (N/256)

  const int tid = threadIdx.x;
  const int l = tid & 63;
  const int wc = tid >> 6;    // 0..3 (N quarter, 64 cols)
  const int li = l & 15;
  const int sl = l >> 4;

  // ---- staging: 6 chunks/thread; dest linear, source pre-swizzled -------
  // chunk -> (row = ch>>2, slot = ch&3); src col = (slot ^ ((row>>1)&3))*8
  const int srow = tid >> 2;                  // 0..63
  const int scol = ((tid & 3) ^ ((tid >> 3) & 3)) * 8;
  const ushort_t* pA0 = A + (size_t)(tile_row * 128 + srow) * N + scol;
  const ushort_t* pA1 = pA0 + (size_t)64 * N;
  const ushort_t* pB0 = B + (size_t)(tile_col * 256 + srow) * N + scol;
  const ushort_t* pB1 = pB0 + (size_t)64 * N;
  const ushort_t* pB2 = pB0 + (size_t)128 * N;
  const ushort_t* pB3 = pB0 + (size_t)192 * N;

#define GLD(SRC, DST)                                              \
  __builtin_amdgcn_global_load_lds(                                \
      (__attribute__((address_space(1))) void*)(SRC),              \
      (__attribute__((address_space(3))) void*)(DST), 16, 0, 0)
#define STG(KO, BUFB) {                                            \
    GLD(pA0 + (KO), smem + (BUFB) + tid * 16);                     \
    GLD(pA1 + (KO), smem + (BUFB) + 4096 + tid * 16);              \
    GLD(pB0 + (KO), smem + (BUFB) + 8192 + tid * 16);              \
    GLD(pB1 + (KO), smem + (BUFB) + 12288 + tid * 16);             \
    GLD(pB2 + (KO), smem + (BUFB) + 16384 + tid * 16);             \
    GLD(pB3 + (KO), smem + (BUFB) + 20480 + tid * 16); }

  // ---- fragment offsets --------------------------------------------------
  const int ssl = (sl ^ ((li >> 1) & 3)) * 16;
  int offA[8], offB[4];
#pragma unroll
  for (int mf = 0; mf < 8; ++mf) offA[mf] = (mf * 16 + li) * 64 + ssl;
#pragma unroll
  for (int nf = 0; nf < 4; ++nf)
    offB[nf] = 8192 + (wc * 64 + nf * 16 + li) * 64 + ssl;

  bf16x8 aX[8], aY[8], bQ0, bQ1, bQ2, bQ3;
  f32x4 acc[8][4];
#pragma unroll
  for (int m = 0; m < 8; ++m)
#pragma unroll
    for (int n = 0; n < 4; ++n) acc[m][n] = (f32x4){0.f, 0.f, 0.f, 0.f};

#define R1(AN, BUFB) { _Pragma("unroll")                                      \
    for (int mf = 0; mf < 8; ++mf)                                            \
      AN[mf] = *(const bf16x8*)(smem + (BUFB) + offA[mf]);                    \
    bQ0 = *(const bf16x8*)(smem + (BUFB) + offB[0]);                          \
    bQ1 = *(const bf16x8*)(smem + (BUFB) + offB[1]); }
#define R2(BUFB) {                                                            \
    bQ2 = *(const bf16x8*)(smem + (BUFB) + offB[2]);                          \
    bQ3 = *(const bf16x8*)(smem + (BUFB) + offB[3]); }

#define MF01(AC) {                                                            \
    __builtin_amdgcn_s_setprio(1);                                            \
    _Pragma("unroll") for (int mf = 0; mf < 8; ++mf) {                        \
      acc[mf][0] = __builtin_amdgcn_mfma_f32_16x16x32_bf16(AC[mf], bQ0,       \
                                                           acc[mf][0], 0,0,0);\
      acc[mf][1] = __builtin_amdgcn_mfma_f32_16x16x32_bf16(AC[mf], bQ1,       \
                                                           acc[mf][1], 0,0,0);\
    }                                                                         \
    __builtin_amdgcn_s_setprio(0); }
#define MF23(AC) {                                                            \
    __builtin_amdgcn_s_setprio(1);                                            \
    _Pragma("unroll") for (int mf = 0; mf < 8; ++mf) {                        \
      acc[mf][2] = __builtin_amdgcn_mfma_f32_16x16x32_bf16(AC[mf], bQ2,       \
                                                           acc[mf][2], 0,0,0);\
      acc[mf][3] = __builtin_amdgcn_mfma_f32_16x16x32_bf16(AC[mf], bQ3,       \
                                                           acc[mf][3], 0,0,0);\
    }                                                                         \
    __builtin_amdgcn_s_setprio(0); }

#define SB    __builtin_amdgcn_sched_barrier(0);
#define BAR   __builtin_amdgcn_s_barrier();
#define LGW2  { asm volatile("s_waitcnt lgkmcnt(2)" ::: "memory"); SB }
#define LGW10 { asm volatile("s_waitcnt lgkmcnt(10)" ::: "memory"); SB }
#define LGW0  { asm volatile("s_waitcnt lgkmcnt(0)" ::: "memory"); SB }
#define VMW6  asm volatile("s_waitcnt vmcnt(6)" ::: "memory");
#define VMW0  asm volatile("s_waitcnt vmcnt(0)" ::: "memory");

  // body(T): compute tile T from CURB; stage T+2 -> STGB; prefetch T+1 reads
#define BODY(CURB, NXTB, STGB, ACUR, ANXT, KO) {                              \
    R2(CURB);                                                                 \
    STG(KO, STGB);                                                            \
    LGW2;                                                                     \
    MF01(ACUR);                                                               \
    VMW6;                                                                     \
    BAR; SB;                                                                  \
    R1(ANXT, NXTB);                                                           \
    LGW10;                                                                    \
    MF23(ACUR);                                                               \
    BAR; SB; }

  // ---- prologue: stage T0->buf0, T1->buf1; publish T0; prime R1(0) ------
  STG(0, 0);
  STG(32, 24576);
  VMW6;
  BAR; SB;
  R1(aX, 0);

  // ---- main loop: 21 iters x 6 tiles = T 0..125 -------------------------
#pragma unroll 1
  for (int it = 0; it < 21; ++it) {
    BODY(0,     24576, 49152, aX, aY, 64);    // T%6==0
    BODY(24576, 49152, 0,     aY, aX, 96);    // 1
    BODY(49152, 0,     24576, aX, aY, 128);   // 2
    BODY(0,     24576, 49152, aY, aX, 160);   // 3
    BODY(24576, 49152, 0,     aX, aY, 192);   // 4
    BODY(49152, 0,     24576, aY, aX, 224);   // 5
    pA0 += 192; pA1 += 192;
    pB0 += 192; pB1 += 192; pB2 += 192; pB3 += 192;
  }

  // ---- tail: T=126 (buf0, cur aX), T=127 (buf1, cur aY) ------------------
  R2(0);
  LGW2;
  MF01(aX);
  VMW0;
  BAR; SB;
  R1(aY, 24576);
  LGW10;
  MF23(aX);
  BAR; SB;

  R2(24576);
  LGW2;
  MF01(aY);
  LGW0;
  MF23(aY);

  // ---- epilogue: cosine normalize; C/D layout row=(l>>4)*4+r, col=l&15 --
  const float* nx = norms;
  const float* ny = norms + N;
#pragma unroll
  for (int mf = 0; mf < 8; ++mf) {
#pragma unroll
    for (int rr = 0; rr < 4; ++rr) {
      const int row = tile_row * 128 + mf * 16 + sl * 4 + rr;
      const float nxr = nx[row];
#pragma unroll
      for (int nf = 0; nf < 4; ++nf) {
        const int col = tile_col * 256 + wc * 64 + nf * 16 + li;
        const float denom = fmaxf(nxr * ny[col], 1e-8f);
        out[(size_t)row * N + col] = acc[mf][nf][rr] / denom;
      }
    }
  }
}

extern "C" void kernel_launch(void* const* d_in, const int* in_sizes, int n_in,
                              void* d_out, int out_size, void* d_ws, size_t ws_size,
                              hipStream_t stream) {
  const float* Z = (const float*)d_in[0];
  const float* Y = (const float*)d_in[1];
  float* out = (float*)d_out;

  ushort_t* Zb = (ushort_t*)d_ws;
  ushort_t* Yb = Zb + (size_t)N * N;
  float* norms = (float*)(Yb + (size_t)N * N);

  prep_kernel<<<2 * N, 256, 0, stream>>>(Z, Y, Zb, Yb, norms);
  gemm_kernel<<<(N / 128) * (N / 256), 256, 0, stream>>>(Zb, Yb, norms, out);
}

// Round 14
// 90.420 us; speedup vs baseline: 1.8509x; 1.8509x over previous
//
#include <hip/hip_runtime.h>

typedef __attribute__((ext_vector_type(4))) int i32x4;

#define N 4096

// One block per row (8192 rows: Z then Y). fp32 row norm + absmax + i8 quant.
__global__ __launch_bounds__(256) void prep_kernel(
    const float* __restrict__ Z, const float* __restrict__ Y,
    char* __restrict__ Zq, char* __restrict__ Yq,
    float* __restrict__ norms, float* __restrict__ scales) {
  const int r = blockIdx.x;
  const bool isZ = (r < N);
  const int rr = isZ ? r : r - N;
  const float* __restrict__ src = (isZ ? Z : Y) + (size_t)rr * N;
  char* __restrict__ dst = (isZ ? Zq : Yq) + (size_t)rr * N;
  const int t = threadIdx.x;

  float4 v[4];
  float s = 0.f, amax = 0.f;
#pragma unroll
  for (int j = 0; j < 4; ++j) {
    v[j] = ((const float4*)src)[t * 4 + j];   // lane owns bytes [64t, 64t+64)
    s += v[j].x * v[j].x + v[j].y * v[j].y + v[j].z * v[j].z + v[j].w * v[j].w;
    amax = fmaxf(amax, fmaxf(fmaxf(fabsf(v[j].x), fabsf(v[j].y)),
                             fmaxf(fabsf(v[j].z), fabsf(v[j].w))));
  }
#pragma unroll
  for (int off = 32; off > 0; off >>= 1) {
    s += __shfl_down(s, off, 64);
    amax = fmaxf(amax, __shfl_down(amax, off, 64));
  }
  __shared__ float reds[4], redm[4];
  const int lane = t & 63, w = t >> 6;
  if (lane == 0) { reds[w] = s; redm[w] = amax; }
  __syncthreads();
  const float bmax = fmaxf(fmaxf(redm[0], redm[1]), fmaxf(redm[2], redm[3]));
  if (t == 0) {
    norms[r] = sqrtf(reds[0] + reds[1] + reds[2] + reds[3]);
    scales[r] = bmax * (1.0f / 127.0f);
  }
  const float inv = (bmax > 0.f) ? (127.0f / bmax) : 0.f;
  int q[16];
#pragma unroll
  for (int j = 0; j < 4; ++j) {
    q[4 * j + 0] = __float2int_rn(v[j].x * inv);
    q[4 * j + 1] = __float2int_rn(v[j].y * inv);
    q[4 * j + 2] = __float2int_rn(v[j].z * inv);
    q[4 * j + 3] = __float2int_rn(v[j].w * inv);
  }
  int4 o;
  o.x = (q[0] & 255) | ((q[1] & 255) << 8) | ((q[2] & 255) << 16) | (q[3] << 24);
  o.y = (q[4] & 255) | ((q[5] & 255) << 8) | ((q[6] & 255) << 16) | (q[7] << 24);
  o.z = (q[8] & 255) | ((q[9] & 255) << 8) | ((q[10] & 255) << 16) | (q[11] << 24);
  o.w = (q[12] & 255) | ((q[13] & 255) << 8) | ((q[14] & 255) << 16) | (q[15] << 24);
  ((int4*)dst)[t] = o;
}

// ---- 256x256 tile, K-tile = 128 i8 (= 128B/row, byte-identical to r11) --
// 8 waves, 2-deep dbuf, 8-phase, reads pipelined one phase ahead with
// counted lgkmcnt, vmcnt(2) gates (r11 schedule verbatim). MFMA:
// mfma_i32_16x16x64_i8 (2x bf16 rate; exact i32 accumulation).
// Regions per buf: A0@0 A1@16K B0@32K B1@48K; buf1 = +64K.
// Swizzle: 16B slot ^= (row & 7), both sides (involution).
__global__ __launch_bounds__(512, 2) void gemm_kernel(
    const char* __restrict__ A,       // Zq [N][N] i8
    const char* __restrict__ B,       // Yq [N][N] i8
    const float* __restrict__ norms,  // [2N]: nx then ny
    const float* __restrict__ scales, // [2N]: sx then sy
    float* __restrict__ out) {
  __shared__ __align__(16) char smem[131072];

  const int bid = blockIdx.x;                 // 256 blocks; bijective
  const int swz = (bid & 7) * 32 + (bid >> 3);
  const int tile_row = swz >> 4;
  const int tile_col = swz & 15;

  const int tid = threadIdx.x;
  const int l = tid & 63;
  const int w = tid >> 6;
  const int wr = w >> 2;      // 0..1
  const int wc = w & 3;       // 0..3
  const int li = l & 15;
  const int sl = l >> 4;

  // ---- staging pointers: 8 per-thread pre-swizzled sources (bytes) ------
  const char *pA00, *pA01, *pA10, *pA11, *pB00, *pB01, *pB10, *pB11;
  {
    const int ch0 = tid, ch1 = 512 + tid;
    const int r0 = ch0 >> 3, r1 = ch1 >> 3;
    const int c0 = ((ch0 & 7) ^ (r0 & 7)) * 16;
    const int c1 = ((ch1 & 7) ^ (r1 & 7)) * 16;
    pA00 = A + (size_t)(tile_row * 256 + r0) * N + c0;
    pA01 = A + (size_t)(tile_row * 256 + r1) * N + c1;
    pA10 = A + (size_t)(tile_row * 256 + 128 + r0) * N + c0;
    pA11 = A + (size_t)(tile_row * 256 + 128 + r1) * N + c1;
    pB00 = B + (size_t)(tile_col * 256 + r0) * N + c0;
    pB01 = B + (size_t)(tile_col * 256 + r1) * N + c1;
    pB10 = B + (size_t)(tile_col * 256 + 128 + r0) * N + c0;
    pB11 = B + (size_t)(tile_col * 256 + 128 + r1) * N + c1;
  }

#define GLD(SRC, DST)                                              \
  __builtin_amdgcn_global_load_lds(                                \
      (__attribute__((address_space(1))) void*)(SRC),              \
      (__attribute__((address_space(3))) void*)(DST), 16, 0, 0)
#define STG(REGOFF, P0, P1, KOFF) {                                \
    GLD((P0) + (KOFF), smem + (REGOFF) + w * 1024);                \
    GLD((P1) + (KOFF), smem + (REGOFF) + 8192 + w * 1024); }

  // ---- fragment addressing (bytes; identical to r11) --------------------
  const int rbA = (wr * 64 + li) * 128;
  const int rbB = (wc * 32 + li) * 128;
  const int sx0 = ((sl) ^ (li & 7)) * 16;
  const int sx1 = ((4 + sl) ^ (li & 7)) * 16;

  i32x4 aC[4][2], bQ0[2][2], bQ1[2][2];
  i32x4 acc[8][4];
#pragma unroll
  for (int m = 0; m < 8; ++m)
#pragma unroll
    for (int n = 0; n < 4; ++n) acc[m][n] = (i32x4){0, 0, 0, 0};

#define RD_A(BUFB, QH) { _Pragma("unroll")                                    \
    for (int mfl = 0; mfl < 4; ++mfl) {                                       \
      aC[mfl][0] = *(const i32x4*)(smem + (BUFB) + (QH)*16384 + rbA +         \
                                   mfl*2048 + sx0);                           \
      aC[mfl][1] = *(const i32x4*)(smem + (BUFB) + (QH)*16384 + rbA +         \
                                   mfl*2048 + sx1); } }
#define RD_B(DST, BUFB, QH) { _Pragma("unroll")                               \
    for (int nfl = 0; nfl < 2; ++nfl) {                                       \
      DST[nfl][0] = *(const i32x4*)(smem + (BUFB) + 32768 + (QH)*16384 +      \
                                    rbB + nfl*2048 + sx0);                    \
      DST[nfl][1] = *(const i32x4*)(smem + (BUFB) + 32768 + (QH)*16384 +      \
                                    rbB + nfl*2048 + sx1); } }

#define MFQ(QM, QN, BF) {                                                     \
    __builtin_amdgcn_s_setprio(1);                                            \
    _Pragma("unroll") for (int kh = 0; kh < 2; ++kh)                          \
    _Pragma("unroll") for (int mfl = 0; mfl < 4; ++mfl)                       \
    _Pragma("unroll") for (int nfl = 0; nfl < 2; ++nfl)                       \
      acc[(QM)*4+mfl][(QN)*2+nfl] = __builtin_amdgcn_mfma_i32_16x16x64_i8(    \
          aC[mfl][kh], BF[nfl][kh], acc[(QM)*4+mfl][(QN)*2+nfl], 0, 0, 0);    \
    __builtin_amdgcn_s_setprio(0); }

#define SB   __builtin_amdgcn_sched_barrier(0);
#define BAR  __builtin_amdgcn_s_barrier();
#define VMW2 asm volatile("s_waitcnt vmcnt(2)" ::: "memory");
#define VMW4 asm volatile("s_waitcnt vmcnt(4)" ::: "memory");
#define VMW0 asm volatile("s_waitcnt vmcnt(0)" ::: "memory");
#define LGW4 { asm volatile("s_waitcnt lgkmcnt(4)" ::: "memory"); SB }
#define LGW0 { asm volatile("s_waitcnt lgkmcnt(0)" ::: "memory"); SB }

  // ---- prologue: stage T0 (A0,B0,B1,A1), gate first half, prime q0 ------
  STG(0, pA00, pA01, 0);          // A0(T0)
  STG(32768, pB00, pB01, 0);      // B0(T0)
  STG(49152, pB10, pB11, 0);      // B1(T0)
  STG(16384, pA10, pA11, 0);      // A1(T0)
  VMW4; BAR; SB;
  RD_A(0, 0); RD_B(bQ0, 0, 0);    // q0(T0)

  // ---- main loop: iter k computes K-tiles T=2k (buf0), T+1 (buf1) -------
  // K = 4096 i8 = 32 tiles of 128 -> 15 iters + 2-tile tail.
#pragma unroll 1
  for (int k = 0; k < 15; ++k) {
    // ph1: Q00(T); stage A0(T+1)
    VMW2; BAR; SB;
    RD_B(bQ1, 0, 1);
    STG(65536, pA00, pA01, 128);
    LGW4;
    MFQ(0, 0, bQ0);
    // ph2: Q01(T); stage B0(T+1)
    VMW2; BAR;
    STG(98304, pB00, pB01, 128);
    LGW0;
    MFQ(0, 1, bQ1);
    SB;
    RD_A(0, 1);
    // ph3: Q11(T); stage B1(T+1)
    BAR;
    STG(114688, pB10, pB11, 128);
    LGW0;
    MFQ(1, 1, bQ1);
    // ph4: Q10(T); stage A1(T+1)
    VMW2; BAR;
    STG(81920, pA10, pA11, 128);
    MFQ(1, 0, bQ0);
    SB;
    RD_A(65536, 0); RD_B(bQ0, 65536, 0);   // q0(T+1)
    // ph5: Q00(T+1); stage A0(T+2)
    VMW2; BAR; SB;
    RD_B(bQ1, 65536, 1);
    STG(0, pA00, pA01, 256);
    LGW4;
    MFQ(0, 0, bQ0);
    // ph6: Q01(T+1); stage B0(T+2)
    VMW2; BAR;
    STG(32768, pB00, pB01, 256);
    LGW0;
    MFQ(0, 1, bQ1);
    SB;
    RD_A(65536, 1);
    // ph7: Q11(T+1); stage B1(T+2)
    BAR;
    STG(49152, pB10, pB11, 256);
    LGW0;
    MFQ(1, 1, bQ1);
    // ph8: Q10(T+1); stage A1(T+2)
    VMW2; BAR;
    STG(16384, pA10, pA11, 256);
    MFQ(1, 0, bQ0);
    SB;
    RD_A(0, 0); RD_B(bQ0, 0, 0);           // q0(T+2)
    pA00 += 256; pA01 += 256; pA10 += 256; pA11 += 256;
    pB00 += 256; pB01 += 256; pB10 += 256; pB11 += 256;
  }

  // ---- tail: T=30 (buf0), T=31 (buf1); stage T31 in t-ph1..4 ------------
  // t-ph1
  VMW2; BAR; SB;
  RD_B(bQ1, 0, 1);
  STG(65536, pA00, pA01, 128);
  LGW4;
  MFQ(0, 0, bQ0);
  // t-ph2
  VMW2; BAR;
  STG(98304, pB00, pB01, 128);
  LGW0;
  MFQ(0, 1, bQ1);
  SB;
  RD_A(0, 1);
  // t-ph3
  BAR;
  STG(114688, pB10, pB11, 128);
  LGW0;
  MFQ(1, 1, bQ1);
  // t-ph4
  VMW2; BAR;
  STG(81920, pA10, pA11, 128);
  MFQ(1, 0, bQ0);
  SB;
  RD_A(65536, 0); RD_B(bQ0, 65536, 0);
  // t-ph5
  VMW2; BAR; SB;
  RD_B(bQ1, 65536, 1);
  LGW4;
  MFQ(0, 0, bQ0);
  // t-ph6
  VMW0; BAR;
  LGW0;
  MFQ(0, 1, bQ1);
  SB;
  RD_A(65536, 1);
  // t-ph7
  LGW0;
  MFQ(1, 1, bQ1);
  // t-ph8
  MFQ(1, 0, bQ0);

  // ---- epilogue: sim = acc * sx*sy / max(nx*ny, 1e-8) -------------------
  // C/D layout (16x16, dtype-independent): row=(l>>4)*4+r, col=l&15
  const float* nx = norms;
  const float* ny = norms + N;
  const float* sxp = scales;
  const float* syp = scales + N;
#pragma unroll
  for (int mf = 0; mf < 8; ++mf) {
#pragma unroll
    for (int r = 0; r < 4; ++r) {
      const int row = tile_row * 256 + (mf >> 2) * 128 + wr * 64 +
                      (mf & 3) * 16 + sl * 4 + r;
      const float nxr = nx[row];
      const float sxr = sxp[row];
#pragma unroll
      for (int nf = 0; nf < 4; ++nf) {
        const int col = tile_col * 256 + (nf >> 1) * 128 + wc * 32 +
                        (nf & 1) * 16 + li;
        const float denom = fmaxf(nxr * ny[col], 1e-8f);
        out[(size_t)row * N + col] =
            (float)acc[mf][nf][r] * (sxr * syp[col]) / denom;
      }
    }
  }
}

extern "C" void kernel_launch(void* const* d_in, const int* in_sizes, int n_in,
                              void* d_out, int out_size, void* d_ws, size_t ws_size,
                              hipStream_t stream) {
  const float* Z = (const float*)d_in[0];
  const float* Y = (const float*)d_in[1];
  float* out = (float*)d_out;

  // workspace: Zq (16MB) | Yq (16MB) | norms (32KB) | scales (32KB)
  char* Zq = (char*)d_ws;
  char* Yq = Zq + (size_t)N * N;
  float* norms = (float*)(Yq + (size_t)N * N);
  float* scales = norms + 2 * N;

  prep_kernel<<<2 * N, 256, 0, stream>>>(Z, Y, Zq, Yq, norms, scales);
  gemm_kernel<<<(N / 256) * (N / 256), 512, 0, stream>>>(Zq, Yq, norms, scales,
                                                         out);
}